// Round 2
// baseline (599.167 us; speedup 1.0000x reference)
//
#include <hip/hip_runtime.h>
#include <hip/hip_cooperative_groups.h>

namespace cg = cooperative_groups;

namespace {

constexpr int Bsz = 8, NC = 10, BC = 80, S = 512, H = 768, G4 = 3072, H2 = 1536;
constexpr int NSP = 8, SCH = 64;          // 8 chunks of 64 rows for kernel A
constexpr int BLK = 256, THR = 384;       // cooperative tail: 256 blocks x 6 waves

__device__ __forceinline__ float sigm(float x){ return 1.0f/(1.0f + __expf(-x)); }
__device__ __forceinline__ float tanh_fast(float x){ return 1.0f - 2.0f/(__expf(2.0f*x) + 1.0f); }

__device__ __forceinline__ float wred(float v){
  #pragma unroll
  for (int m = 32; m; m >>= 1) v += __shfl_xor(v, m, 64);
  return v;
}
__device__ __forceinline__ float dot4(float4 a, float4 b){
  return a.x*b.x + a.y*b.y + a.z*b.z + a.w*b.w;
}

// ================= Kernel A: fused scores -> windowed -> weighted ============
// grid = BC*NSP blocks of 256. Block (bc,ch): rows s0..s0+63, halo +-2.
__global__ __launch_bounds__(256) void k_fusedA(
    const float* __restrict__ tok, const float* __restrict__ w_tok,
    const float* __restrict__ b_tok, float* __restrict__ win_out,
    float* __restrict__ wpart){
  int bc = blockIdx.x >> 3, ch = blockIdx.x & 7;
  int tid = threadIdx.x, lane = tid & 63, wv = tid >> 6;
  __shared__ float scr[SCH + 4];
  __shared__ float wsh[SCH];
  int s0 = ch * SCH;

  const float4* w4 = (const float4*)w_tok;
  float4 q0 = w4[lane], q1 = w4[lane + 64], q2 = w4[lane + 128];
  float btok = b_tok[0];

  // scores for 68 rows (17 per wave)
  #pragma unroll
  for (int k = 0; k < 17; k++){
    int r = wv * 17 + k;
    int gs = s0 - 2 + r;
    float sc = 0.f;
    if (gs >= 0 && gs < S){
      const float4* t4 = (const float4*)(tok + ((size_t)bc * S + gs) * H);
      float acc = dot4(t4[lane], q0) + dot4(t4[lane+64], q1) + dot4(t4[lane+128], q2);
      acc = wred(acc);
      sc = sigm(acc + btok);
    }
    if (lane == 0) scr[r] = sc;
  }
  __syncthreads();
  if (tid < SCH){
    float w = (scr[tid] + scr[tid+1] + scr[tid+2] + scr[tid+3] + scr[tid+4]) * 0.2f;
    wsh[tid] = w;
    win_out[(size_t)bc * S + s0 + tid] = w;
  }
  __syncthreads();
  // weighted accumulate: each thread owns 3 consecutive floats (256*3 = 768)
  const float* base = tok + ((size_t)bc * S + s0) * H + tid * 3;
  float a0 = 0.f, a1 = 0.f, a2 = 0.f;
  #pragma unroll 4
  for (int s = 0; s < SCH; s++){
    float w = wsh[s];
    const float* p = base + (size_t)s * H;
    a0 += p[0] * w; a1 += p[1] * w; a2 += p[2] * w;
  }
  float* op = wpart + ((size_t)(ch * BC + bc)) * H + tid * 3;
  op[0] = a0; op[1] = a1; op[2] = a2;
}

// ================= Kernel B: cooperative tail ================================
struct TailArgs {
  const float *tok, *w_sum, *b_sum, *w_proj, *b_proj;
  const float *w_ih_f, *w_hh_f, *b_ih_f, *b_hh_f;
  const float *w_ih_b, *b_ih_b, *b_hh_b;
  const float *w_cls, *b_cls;
  const float *wpart;
  float *wmean, *s1, *summ_out, *xg, *gbwd, *gA, *gB, *glob, *cls_out;
};

__global__ __launch_bounds__(THR) void k_tail(TailArgs A){
  cg::grid_group grid = cg::this_grid();
  __shared__ float csh[Bsz * H];
  __shared__ float hsh[Bsz * H];
  int tid = threadIdx.x, lane = tid & 63, wv = tid >> 6;
  int gid = blockIdx.x * (THR / 64) + wv;       // 0..1535

  // ---- P0: wmean[b][h] = 0.1 * sum over 8 partials x 10 chunks ----
  int idx = blockIdx.x * THR + tid;
  if (idx < Bsz * H){
    int b = idx / H, h = idx - b * H;
    float acc = 0.f;
    for (int p = 0; p < NSP; p++)
      #pragma unroll
      for (int c = 0; c < NC; c++)
        acc += A.wpart[((size_t)(p * BC + b * NC + c)) * H + h];
    A.wmean[idx] = acc * 0.1f;
  }
  grid.sync();

  // ---- P1: s1 = wmean @ w_sum.T + b_sum (768 rows, wave per row) ----
  if (gid < H){
    const float4* w4 = (const float4*)(A.w_sum + (size_t)gid * H);
    float4 u0 = w4[lane], u1 = w4[lane+64], u2 = w4[lane+128];
    float bb = A.b_sum[gid];
    #pragma unroll
    for (int b = 0; b < Bsz; b++){
      const float4* a4 = (const float4*)(A.wmean + (size_t)b * H);
      float acc = dot4(a4[lane],u0) + dot4(a4[lane+64],u1) + dot4(a4[lane+128],u2);
      acc = wred(acc);
      if (lane == 0) A.s1[(size_t)b * H + gid] = acc + bb;
    }
  }
  grid.sync();

  // ---- P2a: summ_out = s1 @ w_proj.T + b_proj (1536 rows, wave per row) ----
  {
    const float4* w4 = (const float4*)(A.w_proj + (size_t)gid * H);
    float4 u0 = w4[lane], u1 = w4[lane+64], u2 = w4[lane+128];
    float bb = A.b_proj[gid];
    #pragma unroll
    for (int b = 0; b < Bsz; b++){
      const float4* a4 = (const float4*)(A.s1 + (size_t)b * H);
      float acc = dot4(a4[lane],u0) + dot4(a4[lane+64],u1) + dot4(a4[lane+128],u2);
      acc = wred(acc);
      if (lane == 0) A.summ_out[(size_t)b * H2 + gid] = acc + bb;
    }
  }
  // ---- P2b: forward x-gates, xg[bc][g] (2 rows per wave, 80 batches) ----
  {
    int r0 = gid * 2, r1 = r0 + 1;
    const float4* wa = (const float4*)(A.w_ih_f + (size_t)r0 * H);
    const float4* wb = (const float4*)(A.w_ih_f + (size_t)r1 * H);
    float4 u0 = wa[lane], u1 = wa[lane+64], u2 = wa[lane+128];
    float4 v0 = wb[lane], v1 = wb[lane+64], v2 = wb[lane+128];
    float bb0 = A.b_ih_f[r0] + A.b_hh_f[r0];
    float bb1 = A.b_ih_f[r1] + A.b_hh_f[r1];
    for (int i = 0; i < BC; i++){
      const float4* a4 = (const float4*)(A.tok + (size_t)i * S * H);
      float4 a0 = a4[lane], a1 = a4[lane+64], a2 = a4[lane+128];
      float p = dot4(a0,u0) + dot4(a1,u1) + dot4(a2,u2);
      float q = dot4(a0,v0) + dot4(a1,v1) + dot4(a2,v2);
      #pragma unroll
      for (int m = 32; m; m >>= 1){ p += __shfl_xor(p,m,64); q += __shfl_xor(q,m,64); }
      if (lane == 0){
        A.xg[(size_t)i * G4 + r0] = p + bb0;
        A.xg[(size_t)i * G4 + r1] = q + bb1;
      }
    }
  }
  // ---- P2c: backward x-gates (only chunk t=9, 8 batches) ----
  {
    int r0 = gid * 2, r1 = r0 + 1;
    const float4* wa = (const float4*)(A.w_ih_b + (size_t)r0 * H);
    const float4* wb = (const float4*)(A.w_ih_b + (size_t)r1 * H);
    float4 u0 = wa[lane], u1 = wa[lane+64], u2 = wa[lane+128];
    float4 v0 = wb[lane], v1 = wb[lane+64], v2 = wb[lane+128];
    float bb0 = A.b_ih_b[r0] + A.b_hh_b[r0];
    float bb1 = A.b_ih_b[r1] + A.b_hh_b[r1];
    #pragma unroll
    for (int b = 0; b < Bsz; b++){
      const float4* a4 = (const float4*)(A.tok + ((size_t)b * NC + NC - 1) * (size_t)S * H);
      float4 a0 = a4[lane], a1 = a4[lane+64], a2 = a4[lane+128];
      float p = dot4(a0,u0) + dot4(a1,u1) + dot4(a2,u2);
      float q = dot4(a0,v0) + dot4(a1,v1) + dot4(a2,v2);
      #pragma unroll
      for (int m = 32; m; m >>= 1){ p += __shfl_xor(p,m,64); q += __shfl_xor(q,m,64); }
      if (lane == 0){
        A.gbwd[(size_t)b * G4 + r0] = p + bb0;
        A.gbwd[(size_t)b * G4 + r1] = q + bb1;
      }
    }
  }
  grid.sync();

  // ---- LSTM recurrence: g0 = xg[:,0,:]; steps t=1..9 ----
  for (int t = 1; t <= 9; t++){
    const float* gsrc; size_t bstride;
    if (t == 1){ gsrc = A.xg; bstride = (size_t)NC * G4; }          // gates(0) = xg slice t=0
    else       { gsrc = (t & 1) ? A.gB : A.gA; bstride = G4; }      // buffer of step t-1
    for (int i = tid; i < Bsz * H; i += THR){
      int b = i / H, j = i - b * H;
      const float* gp = gsrc + (size_t)b * bstride + j;
      float ig = gp[0], fg = gp[H], gg = gp[2*H], og = gp[3*H];
      float c = sigm(ig) * tanh_fast(gg);
      if (t > 1) c += sigm(fg) * csh[i];
      float h = sigm(og) * tanh_fast(c);
      csh[i] = c; hsh[i] = h;
    }
    __syncthreads();
    float* gcur = (t & 1) ? A.gA : A.gB;
    int r0 = gid * 2, r1 = r0 + 1;
    const float4* wa = (const float4*)(A.w_hh_f + (size_t)r0 * H);
    const float4* wb = (const float4*)(A.w_hh_f + (size_t)r1 * H);
    float4 u0 = wa[lane], u1 = wa[lane+64], u2 = wa[lane+128];
    float4 v0 = wb[lane], v1 = wb[lane+64], v2 = wb[lane+128];
    #pragma unroll
    for (int b = 0; b < Bsz; b++){
      const float4* h4 = (const float4*)(hsh + b * H);
      float4 a0 = h4[lane], a1 = h4[lane+64], a2 = h4[lane+128];
      float p = dot4(a0,u0) + dot4(a1,u1) + dot4(a2,u2);
      float q = dot4(a0,v0) + dot4(a1,v1) + dot4(a2,v2);
      #pragma unroll
      for (int m = 32; m; m >>= 1){ p += __shfl_xor(p,m,64); q += __shfl_xor(q,m,64); }
      if (lane == 0){
        gcur[(size_t)b * G4 + r0] = p + A.xg[((size_t)b * NC + t) * G4 + r0];
        gcur[(size_t)b * G4 + r1] = q + A.xg[((size_t)b * NC + t) * G4 + r1];
      }
    }
    grid.sync();
  }

  // ---- fin + classifier: block 0 only (g9 in gA, c9 in csh) ----
  if (blockIdx.x == 0){
    for (int i = tid; i < Bsz * H; i += THR){
      int b = i / H, j = i - b * H;
      const float* gp = A.gA + (size_t)b * G4 + j;
      float c10 = sigm(gp[H]) * csh[i] + sigm(gp[0]) * tanh_fast(gp[2*H]);
      float h10 = sigm(gp[3*H]) * tanh_fast(c10);
      const float* gq = A.gbwd + (size_t)b * G4 + j;
      float cb = sigm(gq[0]) * tanh_fast(gq[2*H]);
      float hb = sigm(gq[3*H]) * tanh_fast(cb);
      A.glob[(size_t)b * H2 + j]     = h10;
      A.glob[(size_t)b * H2 + H + j] = hb;
    }
    __syncthreads();
    for (int b = wv; b < Bsz; b += THR / 64){
      const float4* g4 = (const float4*)(A.glob + (size_t)b * H2);
      const float4* s4 = (const float4*)(A.summ_out + (size_t)b * H2);
      const float4* w4 = (const float4*)A.w_cls;
      float acc = 0.f;
      #pragma unroll
      for (int k = 0; k < 6; k++){
        float4 g = g4[lane + k*64], s = s4[lane + k*64], w = w4[lane + k*64];
        acc += (g.x+s.x)*w.x + (g.y+s.y)*w.y + (g.z+s.z)*w.z + (g.w+s.w)*w.w;
      }
      acc = wred(acc);
      if (lane == 0) A.cls_out[b] = sigm(acc + A.b_cls[0]);
    }
  }
}

} // namespace

extern "C" void kernel_launch(void* const* d_in, const int* in_sizes, int n_in,
                              void* d_out, int out_size, void* d_ws, size_t ws_size,
                              hipStream_t stream) {
  const float* tok    = (const float*)d_in[0];
  const float* w_tok  = (const float*)d_in[1];
  const float* b_tok  = (const float*)d_in[2];
  const float* w_sum  = (const float*)d_in[3];
  const float* b_sum  = (const float*)d_in[4];
  const float* w_proj = (const float*)d_in[5];
  const float* b_proj = (const float*)d_in[6];
  const float* w_ih_f = (const float*)d_in[7];
  const float* w_hh_f = (const float*)d_in[8];
  const float* b_ih_f = (const float*)d_in[9];
  const float* b_hh_f = (const float*)d_in[10];
  const float* w_ih_b = (const float*)d_in[11];
  const float* b_ih_b = (const float*)d_in[13];
  const float* b_hh_b = (const float*)d_in[14];
  const float* w_cls  = (const float*)d_in[15];
  const float* b_cls  = (const float*)d_in[16];

  float* out      = (float*)d_out;
  float* cls_out  = out;                 // 8
  float* win_out  = out + 8;             // 80*512
  float* summ_out = out + 8 + BC * S;    // 8*1536

  float* ws     = (float*)d_ws;
  float* wpart  = ws;                         // NSP*BC*H = 491520
  float* wmean  = wpart + (size_t)NSP*BC*H;   // 6144
  float* s1     = wmean + Bsz*H;              // 6144
  float* xg     = s1 + Bsz*H;                 // BC*G4 = 245760
  float* gbwd   = xg + (size_t)BC*G4;         // 24576
  float* gA     = gbwd + Bsz*G4;              // 24576
  float* gB     = gA + Bsz*G4;                // 24576
  float* glob   = gB + Bsz*G4;                // 12288

  k_fusedA<<<BC * NSP, 256, 0, stream>>>(tok, w_tok, b_tok, win_out, wpart);

  TailArgs ta;
  ta.tok = tok; ta.w_sum = w_sum; ta.b_sum = b_sum; ta.w_proj = w_proj; ta.b_proj = b_proj;
  ta.w_ih_f = w_ih_f; ta.w_hh_f = w_hh_f; ta.b_ih_f = b_ih_f; ta.b_hh_f = b_hh_f;
  ta.w_ih_b = w_ih_b; ta.b_ih_b = b_ih_b; ta.b_hh_b = b_hh_b;
  ta.w_cls = w_cls; ta.b_cls = b_cls;
  ta.wpart = wpart; ta.wmean = wmean; ta.s1 = s1; ta.summ_out = summ_out;
  ta.xg = xg; ta.gbwd = gbwd; ta.gA = gA; ta.gB = gB; ta.glob = glob; ta.cls_out = cls_out;

  void* params[] = { &ta };
  hipLaunchCooperativeKernel(reinterpret_cast<void*>(k_tail),
                             dim3(BLK), dim3(THR), params, 0, stream);
}

// Round 3
// 333.573 us; speedup vs baseline: 1.7962x; 1.7962x over previous
//
#include <hip/hip_runtime.h>

namespace {

constexpr int Bsz = 8, NC = 10, BC = 80, S = 512, H = 768, G4 = 3072, H2 = 1536;
constexpr int NSP = 8, SCH = 64;

__device__ __forceinline__ float sigm(float x){ return 1.0f/(1.0f + __expf(-x)); }
__device__ __forceinline__ float tanh_fast(float x){ return 1.0f - 2.0f/(__expf(2.0f*x) + 1.0f); }

__device__ __forceinline__ float wred(float v){
  #pragma unroll
  for (int m = 32; m; m >>= 1) v += __shfl_xor(v, m, 64);
  return v;
}
__device__ __forceinline__ float dot4(float4 a, float4 b){
  return a.x*b.x + a.y*b.y + a.z*b.z + a.w*b.w;
}

// ================= Kernel A: fused scores -> windowed -> weighted ============
// grid = BC*NSP blocks of 256. Block (bc,ch): rows s0..s0+63, halo +-2.
__global__ __launch_bounds__(256) void k_fusedA(
    const float* __restrict__ tok, const float* __restrict__ w_tok,
    const float* __restrict__ b_tok, float* __restrict__ win_out,
    float* __restrict__ wpart){
  int bc = blockIdx.x >> 3, ch = blockIdx.x & 7;
  int tid = threadIdx.x, lane = tid & 63, wv = tid >> 6;
  __shared__ float scr[SCH + 4];
  __shared__ float wsh[SCH];
  int s0 = ch * SCH;

  const float4* w4 = (const float4*)w_tok;
  float4 q0 = w4[lane], q1 = w4[lane + 64], q2 = w4[lane + 128];
  float btok = b_tok[0];

  #pragma unroll
  for (int k = 0; k < 17; k++){
    int r = wv * 17 + k;
    int gs = s0 - 2 + r;
    float sc = 0.f;
    if (gs >= 0 && gs < S){
      const float4* t4 = (const float4*)(tok + ((size_t)bc * S + gs) * H);
      float acc = dot4(t4[lane], q0) + dot4(t4[lane+64], q1) + dot4(t4[lane+128], q2);
      acc = wred(acc);
      sc = sigm(acc + btok);
    }
    if (lane == 0) scr[r] = sc;
  }
  __syncthreads();
  if (tid < SCH){
    float w = (scr[tid] + scr[tid+1] + scr[tid+2] + scr[tid+3] + scr[tid+4]) * 0.2f;
    wsh[tid] = w;
    win_out[(size_t)bc * S + s0 + tid] = w;
  }
  __syncthreads();
  const float* base = tok + ((size_t)bc * S + s0) * H + tid * 3;
  float a0 = 0.f, a1 = 0.f, a2 = 0.f;
  #pragma unroll 4
  for (int s = 0; s < SCH; s++){
    float w = wsh[s];
    const float* p = base + (size_t)s * H;
    a0 += p[0] * w; a1 += p[1] * w; a2 += p[2] * w;
  }
  float* op = wpart + ((size_t)(ch * BC + bc)) * H + tid * 3;
  op[0] = a0; op[1] = a1; op[2] = a2;
}

// ================= x-gates (fwd all 80 rows, bwd t=9 rows), one kernel =======
// fwd: wave per (row-pair, 20-batch group): 1536*4 waves = 1536 blocks
// bwd: wave per row-pair, loop 8 batches:   1536 waves   =  384 blocks
constexpr int XG_FBLK = 1536, XG_BBLK = 384;

__global__ __launch_bounds__(256) void k_xgate(
    const float* __restrict__ tok,
    const float* __restrict__ w_ih_f, const float* __restrict__ b_ih_f, const float* __restrict__ b_hh_f,
    const float* __restrict__ w_ih_b, const float* __restrict__ b_ih_b, const float* __restrict__ b_hh_b,
    float* __restrict__ xg, float* __restrict__ gbwd){
  int tid = threadIdx.x, lane = tid & 63, wv = tid >> 6;
  bool fwd = blockIdx.x < XG_FBLK;
  int rp, i0, ni;
  const float* w; const float* bi_; const float* bh_; float* outp;
  if (fwd){
    int wf = blockIdx.x * 4 + wv;          // 0..6143
    rp = wf >> 2;                           // row pair 0..1535
    int grp = wf & 3;
    i0 = grp * 20; ni = 20;
    w = w_ih_f; bi_ = b_ih_f; bh_ = b_hh_f; outp = xg;
  } else {
    rp = (blockIdx.x - XG_FBLK) * 4 + wv;   // 0..1535
    i0 = 0; ni = Bsz;
    w = w_ih_b; bi_ = b_ih_b; bh_ = b_hh_b; outp = gbwd;
  }
  int r0 = rp * 2, r1 = r0 + 1;
  const float4* wa = (const float4*)(w + (size_t)r0 * H);
  const float4* wb = (const float4*)(w + (size_t)r1 * H);
  float4 u0 = wa[lane], u1 = wa[lane+64], u2 = wa[lane+128];
  float4 v0 = wb[lane], v1 = wb[lane+64], v2 = wb[lane+128];
  float bb0 = bi_[r0] + bh_[r0];
  float bb1 = bi_[r1] + bh_[r1];
  for (int k = 0; k < ni; k++){
    int i = i0 + k;
    size_t bc = fwd ? (size_t)i : ((size_t)i * NC + NC - 1);
    const float4* a4 = (const float4*)(tok + bc * (size_t)S * H);
    float4 a0 = a4[lane], a1 = a4[lane+64], a2 = a4[lane+128];
    float p = dot4(a0,u0) + dot4(a1,u1) + dot4(a2,u2);
    float q = dot4(a0,v0) + dot4(a1,v1) + dot4(a2,v2);
    #pragma unroll
    for (int m = 32; m; m >>= 1){ p += __shfl_xor(p,m,64); q += __shfl_xor(q,m,64); }
    if (lane == 0){
      outp[(size_t)i * G4 + r0] = p + bb0;
      outp[(size_t)i * G4 + r1] = q + bb1;
    }
  }
}

// ================= one LSTM recurrence step s (s = 1..9) =====================
// phase A: (h^s, c^s) from g^s (gsrc) and c^{s-1}; block 0 persists c^s.
// phase B: gdst = xg[:,t=s,:] + h^s @ w_hh.T
__global__ __launch_bounds__(256) void k_step(
    const float* __restrict__ w_hh, const float* __restrict__ xg,
    const float* __restrict__ gsrc, long gstride, const float* __restrict__ cprev,
    float* __restrict__ gdst, float* __restrict__ cdst, int t, int first){
  __shared__ float hsh[Bsz * H];
  int tid = threadIdx.x;
  for (int i = tid; i < Bsz * H; i += 256){
    int b = i / H, j = i - b * H;
    const float* gp = gsrc + (size_t)b * gstride + j;
    float ig = gp[0], fg = gp[H], gg = gp[2*H], og = gp[3*H];
    float c = sigm(ig) * tanh_fast(gg);
    if (!first) c += sigm(fg) * cprev[i];
    float h = sigm(og) * tanh_fast(c);
    hsh[i] = h;
    if (blockIdx.x == 0) cdst[i] = c;
  }
  __syncthreads();
  int lane = tid & 63, wv = tid >> 6;
  int rbase = blockIdx.x * 16 + wv * 4;
  #pragma unroll
  for (int pp = 0; pp < 2; pp++){
    int r0 = rbase + pp * 2, r1 = r0 + 1;
    const float4* wa = (const float4*)(w_hh + (size_t)r0 * H);
    const float4* wb = (const float4*)(w_hh + (size_t)r1 * H);
    float4 u0 = wa[lane], u1 = wa[lane+64], u2 = wa[lane+128];
    float4 v0 = wb[lane], v1 = wb[lane+64], v2 = wb[lane+128];
    #pragma unroll
    for (int b = 0; b < Bsz; b++){
      const float4* h4 = (const float4*)(hsh + b * H);
      float4 a0 = h4[lane], a1 = h4[lane+64], a2 = h4[lane+128];
      float p = dot4(a0,u0) + dot4(a1,u1) + dot4(a2,u2);
      float q = dot4(a0,v0) + dot4(a1,v1) + dot4(a2,v2);
      #pragma unroll
      for (int m = 32; m; m >>= 1){ p += __shfl_xor(p,m,64); q += __shfl_xor(q,m,64); }
      if (lane == 0){
        gdst[(size_t)b * G4 + r0] = p + xg[((size_t)b * NC + t) * G4 + r0];
        gdst[(size_t)b * G4 + r1] = q + xg[((size_t)b * NC + t) * G4 + r1];
      }
    }
  }
}

// ================= wmean / row-GEMMs =========================================
__global__ void k_wmean(const float* __restrict__ wpart, float* __restrict__ wmean){
  int idx = blockIdx.x * blockDim.x + threadIdx.x;
  if (idx >= Bsz * H) return;
  int b = idx / H, h = idx - b * H;
  float acc = 0.f;
  for (int p = 0; p < NSP; p++)
    #pragma unroll
    for (int c = 0; c < NC; c++)
      acc += wpart[((size_t)(p * BC + b * NC + c)) * H + h];
  wmean[idx] = acc * 0.1f;
}

template<int NB>
__global__ void k_gemm_bt(const float* __restrict__ A, const float* __restrict__ W,
                          const float* __restrict__ bias, float* __restrict__ Cout, int no){
  int o = (int)((blockIdx.x * blockDim.x + threadIdx.x) >> 6);
  int lane = threadIdx.x & 63;
  if (o >= no) return;
  const float4* w4 = (const float4*)(W + (size_t)o * H);
  float4 w0 = w4[lane], w1 = w4[lane+64], w2 = w4[lane+128];
  float bb = bias[o];
  #pragma unroll
  for (int b = 0; b < NB; b++){
    const float4* a4 = (const float4*)(A + (size_t)b * H);
    float acc = dot4(a4[lane], w0) + dot4(a4[lane+64], w1) + dot4(a4[lane+128], w2);
    acc = wred(acc);
    if (lane == 0) Cout[(size_t)b * no + o] = acc + bb;
  }
}

// ================= final: h10 + backward step + classifier (1 block) =========
__global__ __launch_bounds__(512) void k_fincls(
    const float* __restrict__ g10, const float* __restrict__ c9,
    const float* __restrict__ gbwd, const float* __restrict__ summ,
    const float* __restrict__ w_cls, const float* __restrict__ b_cls,
    float* __restrict__ cls_out){
  __shared__ float globsh[Bsz * H2];
  int tid = threadIdx.x, lane = tid & 63, wv = tid >> 6;
  for (int i = tid; i < Bsz * H; i += 512){
    int b = i / H, j = i - b * H;
    const float* gp = g10 + (size_t)b * G4 + j;
    float c10 = sigm(gp[H]) * c9[i] + sigm(gp[0]) * tanh_fast(gp[2*H]);
    float h10 = sigm(gp[3*H]) * tanh_fast(c10);
    const float* gq = gbwd + (size_t)b * G4 + j;
    float cb = sigm(gq[0]) * tanh_fast(gq[2*H]);
    float hb = sigm(gq[3*H]) * tanh_fast(cb);
    globsh[b * H2 + j]     = h10;
    globsh[b * H2 + H + j] = hb;
  }
  __syncthreads();
  int b = wv;
  const float4* g4 = (const float4*)(globsh + (size_t)b * H2);
  const float4* s4 = (const float4*)(summ + (size_t)b * H2);
  const float4* w4 = (const float4*)w_cls;
  float acc = 0.f;
  #pragma unroll
  for (int k = 0; k < 6; k++){
    float4 g = g4[lane + k*64], s = s4[lane + k*64], w = w4[lane + k*64];
    acc += (g.x+s.x)*w.x + (g.y+s.y)*w.y + (g.z+s.z)*w.z + (g.w+s.w)*w.w;
  }
  acc = wred(acc);
  if (lane == 0) cls_out[b] = sigm(acc + b_cls[0]);
}

} // namespace

extern "C" void kernel_launch(void* const* d_in, const int* in_sizes, int n_in,
                              void* d_out, int out_size, void* d_ws, size_t ws_size,
                              hipStream_t stream) {
  const float* tok    = (const float*)d_in[0];
  const float* w_tok  = (const float*)d_in[1];
  const float* b_tok  = (const float*)d_in[2];
  const float* w_sum  = (const float*)d_in[3];
  const float* b_sum  = (const float*)d_in[4];
  const float* w_proj = (const float*)d_in[5];
  const float* b_proj = (const float*)d_in[6];
  const float* w_ih_f = (const float*)d_in[7];
  const float* w_hh_f = (const float*)d_in[8];
  const float* b_ih_f = (const float*)d_in[9];
  const float* b_hh_f = (const float*)d_in[10];
  const float* w_ih_b = (const float*)d_in[11];
  const float* b_ih_b = (const float*)d_in[13];
  const float* b_hh_b = (const float*)d_in[14];
  const float* w_cls  = (const float*)d_in[15];
  const float* b_cls  = (const float*)d_in[16];

  float* out      = (float*)d_out;
  float* cls_out  = out;
  float* win_out  = out + 8;
  float* summ_out = out + 8 + BC * S;

  float* ws     = (float*)d_ws;
  float* wpart  = ws;                         // NSP*BC*H
  float* wmean  = wpart + (size_t)NSP*BC*H;   // 6144
  float* s1     = wmean + Bsz*H;              // 6144
  float* xg     = s1 + Bsz*H;                 // BC*G4
  float* gbwd   = xg + (size_t)BC*G4;         // 24576
  float* gA     = gbwd + (size_t)Bsz*G4;      // 24576
  float* gB     = gA + (size_t)Bsz*G4;        // 24576
  float* cA     = gB + (size_t)Bsz*G4;        // 6144
  float* cB     = cA + Bsz*H;                 // 6144

  // big fused pass over token_embeddings
  k_fusedA<<<BC * NSP, 256, 0, stream>>>(tok, w_tok, b_tok, win_out, wpart);
  // x-gates (fwd + bwd) in one kernel
  k_xgate<<<XG_FBLK + XG_BBLK, 256, 0, stream>>>(tok, w_ih_f, b_ih_f, b_hh_f,
                                                 w_ih_b, b_ih_b, b_hh_b, xg, gbwd);
  // LSTM recurrence: g^(1) = xg[:,0,:]; steps s=1..9 produce g^(s+1), c^(s)
  for (int s = 1; s <= 9; s++){
    const float* gsrc = (s == 1) ? xg : ((s & 1) ? gB : gA);
    long gstride      = (s == 1) ? (long)NC * G4 : (long)G4;
    const float* cprev= (s & 1) ? cB : cA;   // unused when s==1
    float* gdst       = (s & 1) ? gA : gB;
    float* cdst       = (s & 1) ? cA : cB;
    k_step<<<192, 256, 0, stream>>>(w_hh_f, xg, gsrc, gstride, cprev, gdst, cdst, s, s == 1);
  }
  // windowed-summary tail
  k_wmean<<<(Bsz * H + 255) / 256, 256, 0, stream>>>(wpart, wmean);
  k_gemm_bt<Bsz><<<(H * 64) / 256, 256, 0, stream>>>(wmean, w_sum, b_sum, s1, H);
  k_gemm_bt<Bsz><<<(H2 * 64) / 256, 256, 0, stream>>>(s1, w_proj, b_proj, summ_out, H2);
  // final: g^(10) in gA, c^(9) in cA
  k_fincls<<<1, 512, 0, stream>>>(gA, cA, gbwd, summ_out, w_cls, b_cls, cls_out);
}